// Round 1
// baseline (1629.610 us; speedup 1.0000x reference)
//
#include <hip/hip_runtime.h>
#include <stdint.h>
#include <stddef.h>

// AttentionGRUCell on MI355X (gfx950).
// B=16384, EMB=1024, HID=1024, COMB=2048.
// Strategy: bf16 MFMA (16x16x32) GEMMs with fused epilogues.
//   R: r = sigmoid(x@Wr + h@Ur + a@Cr)          -> rh = r*h (bf16, ws)
//   Z: z = sigmoid(x@Wz + h@Uz + a@Cz)          -> z (bf16, ws)
//   S: st = tanh(x@W + rh@U + a@C); s=(1-z)h+z*st -> d_out[0:16M) (f32)
//   T: t = relu(x@Vo + s@Uo + a@Co)             -> d_out[16M:32M)
// Weights are transposed+converted to bf16 [N,K] in ws each call (ws is
// re-poisoned before every timed launch, so this must rerun every call).

#define MODE_Z 0
#define MODE_R 1
#define MODE_S 2
#define MODE_T 3

typedef __attribute__((ext_vector_type(8))) __bf16 bf16x8;
typedef __attribute__((ext_vector_type(4))) float f32x4;
typedef __attribute__((ext_vector_type(4))) unsigned short us4;
typedef __attribute__((ext_vector_type(8))) unsigned short us8;

__device__ __forceinline__ unsigned short f2bf(float f) {
  union { float f; unsigned u; } v; v.f = f;
  unsigned r = 0x7FFFu + ((v.u >> 16) & 1u);   // round-to-nearest-even
  return (unsigned short)((v.u + r) >> 16);
}
__device__ __forceinline__ float bf2f(unsigned short h) {
  union { unsigned u; float f; } v; v.u = ((unsigned)h) << 16;
  return v.f;
}

// f32 [K,N] -> bf16 [N,K]  (N always 1024 here; K in {1024,2048})
__global__ void transpose_w(const float* __restrict__ src,
                            unsigned short* __restrict__ dst, int K, int N) {
  __shared__ float tile[32][33];
  int kb = blockIdx.x * 32, nb = blockIdx.y * 32;
  int tx = threadIdx.x, ty = threadIdx.y;   // block 32x8
  #pragma unroll
  for (int i = 0; i < 32; i += 8)
    tile[ty + i][tx] = src[(size_t)(kb + ty + i) * N + nb + tx];
  __syncthreads();
  #pragma unroll
  for (int i = 0; i < 32; i += 8)
    dst[(size_t)(nb + ty + i) * K + kb + tx] = f2bf(tile[tx][ty + i]);
}

// 128x128 output tile, BK=64, 256 threads (4 waves, 2x2), each wave 64x64
// = 4x4 tiles of v_mfma_f32_16x16x32_bf16.
// LDS pad: rows of 72 bf16 (144 B) -> frag ds_read_b128 is 2-way conflict (free).
template <int MODE>
__global__ __launch_bounds__(256, 2)
void gemm_fused(const float* __restrict__ Ax,          // seg0 A, K=1024, f32
                const void* __restrict__ A1,           // seg1 A, K=1024 (f32, or bf16 when MODE_S)
                const float* __restrict__ Aa,          // seg2 A, K=2048, f32
                const unsigned short* __restrict__ B0T, // bf16 [1024,1024]
                const unsigned short* __restrict__ B1T, // bf16 [1024,1024]
                const unsigned short* __restrict__ B2T, // bf16 [1024,2048]
                const float* __restrict__ b0,
                const float* __restrict__ b1,
                const float* __restrict__ b2,
                const float* __restrict__ h,            // last_hid_state (R,S)
                const unsigned short* __restrict__ z_ws,// z bf16 (S)
                void* __restrict__ outp) {
  __shared__ unsigned short As[128][72];
  __shared__ unsigned short Bs[128][72];

  const int tid = threadIdx.x;
  const int mBlk = blockIdx.x >> 3;
  const int nBlk = blockIdx.x & 7;
  const int rowBase = mBlk * 128;
  const int colBase = nBlk * 128;
  const int wave = tid >> 6;
  const int lane = tid & 63;
  const int waveM = wave >> 1;
  const int waveN = wave & 1;
  const int quad = lane >> 4;
  const int lm = lane & 15;

  f32x4 acc[4][4];
  #pragma unroll
  for (int i = 0; i < 4; ++i)
    #pragma unroll
    for (int j = 0; j < 4; ++j)
      acc[i][j] = (f32x4){0.f, 0.f, 0.f, 0.f};

  #pragma unroll
  for (int seg = 0; seg < 3; ++seg) {
    const int K = (seg == 2) ? 2048 : 1024;
    const unsigned short* BT = (seg == 0) ? B0T : (seg == 1) ? B1T : B2T;
    constexpr bool A1BF = (MODE == MODE_S);
    const bool abf = A1BF && (seg == 1);
    const float* Af = (seg == 0) ? Ax : (seg == 1) ? (const float*)A1 : Aa;
    const unsigned short* Ab = (const unsigned short*)A1;

    const int nChunks = K >> 6;
    for (int kc = 0; kc < nChunks; ++kc) {
      // ---- stage A tile: 128 rows x 64 cols ----
      if (!abf) {
        #pragma unroll
        for (int it = 0; it < 8; ++it) {
          int idx = it * 256 + tid;      // 0..2047 float4 units
          int row = idx >> 4;            // 16 float4 per row
          int c4 = idx & 15;
          f32x4 v = *(const f32x4*)(Af + (size_t)(rowBase + row) * K + (kc << 6) + c4 * 4);
          us4 pk = { f2bf(v.x), f2bf(v.y), f2bf(v.z), f2bf(v.w) };
          *(us4*)&As[row][c4 * 4] = pk;
        }
      } else {
        #pragma unroll
        for (int it = 0; it < 4; ++it) {
          int idx = it * 256 + tid;      // 0..1023 ushort8 units
          int row = idx >> 3;            // 8 ushort8 per row
          int c8 = idx & 7;
          us8 v = *(const us8*)(Ab + (size_t)(rowBase + row) * K + (kc << 6) + c8 * 8);
          *(us8*)&As[row][c8 * 8] = v;
        }
      }
      // ---- stage B tile (already bf16, [N,K] layout): 128 rows x 64 cols ----
      #pragma unroll
      for (int it = 0; it < 4; ++it) {
        int idx = it * 256 + tid;
        int row = idx >> 3;
        int c8 = idx & 7;
        us8 v = *(const us8*)(BT + (size_t)(colBase + row) * K + (kc << 6) + c8 * 8);
        *(us8*)&Bs[row][c8 * 8] = v;
      }
      __syncthreads();
      // ---- MFMA: 2 k-steps of 32 ----
      #pragma unroll
      for (int ks = 0; ks < 2; ++ks) {
        bf16x8 af[4], bfr[4];
        #pragma unroll
        for (int i = 0; i < 4; ++i)
          af[i] = *(const bf16x8*)&As[waveM * 64 + i * 16 + lm][ks * 32 + quad * 8];
        #pragma unroll
        for (int j = 0; j < 4; ++j)
          bfr[j] = *(const bf16x8*)&Bs[waveN * 64 + j * 16 + lm][ks * 32 + quad * 8];
        #pragma unroll
        for (int i = 0; i < 4; ++i)
          #pragma unroll
          for (int j = 0; j < 4; ++j)
            acc[i][j] = __builtin_amdgcn_mfma_f32_16x16x32_bf16(af[i], bfr[j], acc[i][j], 0, 0, 0);
      }
      __syncthreads();
    }
  }

  // ---- fused epilogue. C/D layout: col = lane&15, row = quad*4 + reg ----
  #pragma unroll
  for (int j = 0; j < 4; ++j) {
    const int col = colBase + waveN * 64 + j * 16 + lm;
    const float bias = b0[col] + b1[col] + b2[col];
    #pragma unroll
    for (int i = 0; i < 4; ++i) {
      #pragma unroll
      for (int r = 0; r < 4; ++r) {
        const int row = rowBase + waveM * 64 + i * 16 + quad * 4 + r;
        const size_t idx = (size_t)row * 1024 + col;
        float v = acc[i][j][r] + bias;
        if constexpr (MODE == MODE_Z) {
          float zv = 1.f / (1.f + __expf(-v));
          ((unsigned short*)outp)[idx] = f2bf(zv);
        } else if constexpr (MODE == MODE_R) {
          float rv = 1.f / (1.f + __expf(-v));
          ((unsigned short*)outp)[idx] = f2bf(rv * h[idx]);
        } else if constexpr (MODE == MODE_S) {
          float st = tanhf(v);
          float zv = bf2f(z_ws[idx]);
          float hv = h[idx];
          ((float*)outp)[idx] = (1.f - zv) * hv + zv * st;
        } else { // MODE_T
          ((float*)outp)[idx] = v > 0.f ? v : 0.f;
        }
      }
    }
  }
}

extern "C" void kernel_launch(void* const* d_in, const int* in_sizes, int n_in,
                              void* d_out, int out_size, void* d_ws, size_t ws_size,
                              hipStream_t stream) {
  (void)in_sizes; (void)n_in; (void)out_size; (void)ws_size;
  const float* x  = (const float*)d_in[0];   // [16384,1024]
  const float* h  = (const float*)d_in[1];   // [16384,1024]
  const float* a  = (const float*)d_in[2];   // [16384,2048]
  const float* W   = (const float*)d_in[3];  const float* bw  = (const float*)d_in[4];
  const float* Wz  = (const float*)d_in[5];  const float* bwz = (const float*)d_in[6];
  const float* Wr  = (const float*)d_in[7];  const float* bwr = (const float*)d_in[8];
  const float* U   = (const float*)d_in[9];  const float* bu  = (const float*)d_in[10];
  const float* Uz  = (const float*)d_in[11]; const float* buz = (const float*)d_in[12];
  const float* Ur  = (const float*)d_in[13]; const float* bur = (const float*)d_in[14];
  const float* C   = (const float*)d_in[15]; const float* bc  = (const float*)d_in[16];
  const float* Cz  = (const float*)d_in[17]; const float* bcz = (const float*)d_in[18];
  const float* Cr  = (const float*)d_in[19]; const float* bcr = (const float*)d_in[20];
  const float* Uo  = (const float*)d_in[21]; const float* buo = (const float*)d_in[22];
  const float* Vo  = (const float*)d_in[23]; const float* bvo = (const float*)d_in[24];
  const float* Co  = (const float*)d_in[25]; const float* bco = (const float*)d_in[26];

  // ws layout (ushort units). Weights: 16M us = 32MB; z: 16M; rh: 16M. Total 96MB.
  unsigned short* ws = (unsigned short*)d_ws;
  const size_t M1 = 1024u * 1024u;
  unsigned short* WzT = ws + 0 * M1;
  unsigned short* UzT = ws + 1 * M1;
  unsigned short* CzT = ws + 2 * M1;   // len 2M
  unsigned short* WrT = ws + 4 * M1;
  unsigned short* UrT = ws + 5 * M1;
  unsigned short* CrT = ws + 6 * M1;   // len 2M
  unsigned short* WT  = ws + 8 * M1;
  unsigned short* UT  = ws + 9 * M1;
  unsigned short* CT  = ws + 10 * M1;  // len 2M
  unsigned short* VoT = ws + 12 * M1;
  unsigned short* UoT = ws + 13 * M1;
  unsigned short* CoT = ws + 14 * M1;  // len 2M
  unsigned short* z_ws  = ws + 16 * M1;  // 16M us
  unsigned short* rh_ws = ws + 32 * M1;  // 16M us

  dim3 tb(32, 8);
  auto T = [&](const float* s, unsigned short* d, int K) {
    transpose_w<<<dim3(K / 32, 1024 / 32), tb, 0, stream>>>(s, d, K, 1024);
  };
  T(Wz, WzT, 1024); T(Uz, UzT, 1024); T(Cz, CzT, 2048);
  T(Wr, WrT, 1024); T(Ur, UrT, 1024); T(Cr, CrT, 2048);
  T(W,  WT,  1024); T(U,  UT,  1024); T(C,  CT,  2048);
  T(Vo, VoT, 1024); T(Uo, UoT, 1024); T(Co, CoT, 2048);

  float* s_out = (float*)d_out;
  float* t_out = (float*)d_out + (size_t)16384 * 1024;

  dim3 g(1024), b(256);
  gemm_fused<MODE_R><<<g, b, 0, stream>>>(x, (const void*)h, a, WrT, UrT, CrT,
                                          bwr, bur, bcr, h, nullptr, (void*)rh_ws);
  gemm_fused<MODE_Z><<<g, b, 0, stream>>>(x, (const void*)h, a, WzT, UzT, CzT,
                                          bwz, buz, bcz, h, nullptr, (void*)z_ws);
  gemm_fused<MODE_S><<<g, b, 0, stream>>>(x, (const void*)rh_ws, a, WT, UT, CT,
                                          bw, bu, bc, h, z_ws, (void*)s_out);
  gemm_fused<MODE_T><<<g, b, 0, stream>>>(x, (const void*)s_out, a, VoT, UoT, CoT,
                                          bvo, buo, bco, nullptr, nullptr, (void*)t_out);
}

// Round 2
// 1044.396 us; speedup vs baseline: 1.5603x; 1.5603x over previous
//
#include <hip/hip_runtime.h>
#include <stdint.h>
#include <stddef.h>

// AttentionGRUCell on MI355X (gfx950).  B=16384, EMB=1024, HID=1024, COMB=2048.
// All GEMMs bf16 MFMA 16x16x32, 128x128 tiles, BK=64, async global_load_lds
// staging (width 16) with XOR-swizzled LDS to kill bank conflicts, XCD-aware
// block swizzle so A-slabs are shared within one XCD's L2.
//
// Memory choreography (cross-launch ordering makes input buffers reusable):
//   cvt_xh : x,h f32 -> x_bf (ws), h_bf (d_out t-region, dead until T)
//   cvt_a  : a f32   -> a_bf (x's input buffer, x f32 now dead)
//   transpose_all: 12 weights f32 [K,N] -> bf16 [N,K] in ws
//   R: rh = sigmoid(xWr+hUr+aCr)*h -> h-buffer[0:32M)      (h f32 dead)
//   Z: z  = sigmoid(xWz+hUz+aCz)   -> h-buffer[32M:64M)
//   S: s  = (1-z)h + z*tanh(xW+rhU+aC) -> d_out[0:64MB) f32, s_bf -> a-buffer
//   T: t  = relu(xVo+sUo+aCo)      -> d_out[64MB:128MB) f32 (over dead h_bf)

#define MODE_Z 0
#define MODE_R 1
#define MODE_S 2
#define MODE_T 3

typedef __attribute__((ext_vector_type(8))) __bf16 bf16x8;
typedef __attribute__((ext_vector_type(4))) float f32x4;
typedef __attribute__((ext_vector_type(8))) unsigned short us8;

__device__ __forceinline__ unsigned short f2bf(float f) {
  union { float f; unsigned u; } v; v.f = f;
  unsigned r = 0x7FFFu + ((v.u >> 16) & 1u);   // round-to-nearest-even
  return (unsigned short)((v.u + r) >> 16);
}
__device__ __forceinline__ float bf2f(unsigned short h) {
  union { unsigned u; float f; } v; v.u = ((unsigned)h) << 16;
  return v.f;
}

__device__ __forceinline__ void gload_lds16(const unsigned short* g, unsigned short* l) {
  __builtin_amdgcn_global_load_lds(
      (const __attribute__((address_space(1))) void*)g,
      (__attribute__((address_space(3))) void*)l, 16, 0, 0);
}

// ---- f32 -> bf16 converters (8 elems/thread, fully coalesced) ----
__global__ void cvt_xh(const float* __restrict__ x, const float* __restrict__ h,
                       unsigned short* __restrict__ xb, unsigned short* __restrict__ hb) {
  const size_t NX = 16777216;  // 16384*1024
  size_t i = ((size_t)blockIdx.x * 256 + threadIdx.x) * 8;
  const float* s; unsigned short* d; size_t off;
  if (i < NX) { s = x; d = xb; off = i; } else { s = h; d = hb; off = i - NX; }
  f32x4 v0 = *(const f32x4*)(s + off);
  f32x4 v1 = *(const f32x4*)(s + off + 4);
  us8 p = { f2bf(v0.x), f2bf(v0.y), f2bf(v0.z), f2bf(v0.w),
            f2bf(v1.x), f2bf(v1.y), f2bf(v1.z), f2bf(v1.w) };
  *(us8*)(d + off) = p;
}

__global__ void cvt_a(const float* __restrict__ a, unsigned short* __restrict__ ab) {
  size_t i = ((size_t)blockIdx.x * 256 + threadIdx.x) * 8;
  f32x4 v0 = *(const f32x4*)(a + i);
  f32x4 v1 = *(const f32x4*)(a + i + 4);
  us8 p = { f2bf(v0.x), f2bf(v0.y), f2bf(v0.z), f2bf(v0.w),
            f2bf(v1.x), f2bf(v1.y), f2bf(v1.z), f2bf(v1.w) };
  *(us8*)(ab + i) = p;
}

// ---- batched weight transpose: f32 [K,1024] -> bf16 [1024,K] ----
struct TArgs {
  const float* src[12];
  unsigned short* dst[12];
};

__global__ void transpose_all(TArgs ta) {
  __shared__ float tile[32][33];
  int t = blockIdx.x;
  int w, K, local;
  if (t < 8192) { w = t >> 10; K = 1024; local = t & 1023; }
  else { int t2 = t - 8192; w = 8 + (t2 >> 11); K = 2048; local = t2 & 2047; }
  int kb = (K == 1024) ? ((local & 31) << 5) : ((local & 63) << 5);
  int nb = (K == 1024) ? ((local >> 5) << 5) : ((local >> 6) << 5);
  const float* src = ta.src[w];
  unsigned short* dst = ta.dst[w];
  int tx = threadIdx.x, ty = threadIdx.y;   // block 32x8
  #pragma unroll
  for (int i = 0; i < 32; i += 8)
    tile[ty + i][tx] = src[(size_t)(kb + ty + i) * 1024 + nb + tx];
  __syncthreads();
  #pragma unroll
  for (int i = 0; i < 32; i += 8)
    dst[(size_t)(nb + ty + i) * K + kb + tx] = f2bf(tile[tx][ty + i]);
}

// ---- fused GEMM: 128x128 tile, 4 waves 2x2, 4x4 MFMA 16x16x32 each ----
// LDS layout: [row][kgroup] where lds-kgroup = data-kgroup ^ (row&7)
// (XOR swizzle -> frag ds_read_b128 is 2-way bank aliased = free).
template <int MODE>
__global__ __launch_bounds__(256, 4)
void gemm_fused(const unsigned short* __restrict__ A0,   // K=1024
                const unsigned short* __restrict__ A1,   // K=1024
                const unsigned short* __restrict__ A2,   // K=2048
                const unsigned short* __restrict__ B0T,
                const unsigned short* __restrict__ B1T,
                const unsigned short* __restrict__ B2T,
                const float* __restrict__ b0,
                const float* __restrict__ b1,
                const float* __restrict__ b2,
                const unsigned short* __restrict__ hb,   // h bf16 (R,S)
                const unsigned short* __restrict__ zb,   // z bf16 (S)
                float* __restrict__ outf,
                unsigned short* __restrict__ outb) {
  __shared__ unsigned short As[128 * 64];
  __shared__ unsigned short Bs[128 * 64];

  const int tid = threadIdx.x;
  const int bid = blockIdx.x;
  // XCD swizzle: blocks sharing an A-slab (same mBlk, all 8 nBlk) are
  // consecutive within one XCD (dispatch round-robins bid across 8 XCDs).
  const int xcd = bid & 7;
  const int j8 = bid >> 3;                  // 0..127
  const int mBlk = xcd * 16 + (j8 >> 3);
  const int nBlk = j8 & 7;
  const int rowBase = mBlk * 128;
  const int colBase = nBlk * 128;
  const int wave = tid >> 6;
  const int lane = tid & 63;
  const int waveM = wave >> 1;
  const int waveN = wave & 1;
  const int quad = lane >> 4;
  const int lm = lane & 15;
  const int wbase = tid & 192;              // wave * 64

  f32x4 acc[4][4];
  #pragma unroll
  for (int i = 0; i < 4; ++i)
    #pragma unroll
    for (int j = 0; j < 4; ++j)
      acc[i][j] = (f32x4){0.f, 0.f, 0.f, 0.f};

  const unsigned short* Asegs[3] = {A0, A1, A2};
  const unsigned short* Bsegs[3] = {B0T, B1T, B2T};

  #pragma unroll
  for (int seg = 0; seg < 3; ++seg) {
    const int K = (seg == 2) ? 2048 : 1024;
    const unsigned short* Ap = Asegs[seg] + (size_t)rowBase * K;
    const unsigned short* Bp = Bsegs[seg] + (size_t)colBase * K;
    const int nChunks = K >> 6;
    for (int kc = 0; kc < nChunks; ++kc) {
      // ---- async stage A (16 KB) and B (16 KB), 4 glLDS each per thread ----
      #pragma unroll
      for (int t = 0; t < 4; ++t) {
        int idx = t * 256 + tid;
        int row = idx >> 3;
        int kg = (idx & 7) ^ (row & 7);     // swizzled source kgroup
        gload_lds16(Ap + (size_t)row * K + (kc << 6) + (kg << 3),
                    &As[(size_t)(t * 256 + wbase) << 3]);
      }
      #pragma unroll
      for (int t = 0; t < 4; ++t) {
        int idx = t * 256 + tid;
        int row = idx >> 3;
        int kg = (idx & 7) ^ (row & 7);
        gload_lds16(Bp + (size_t)row * K + (kc << 6) + (kg << 3),
                    &Bs[(size_t)(t * 256 + wbase) << 3]);
      }
      __syncthreads();
      // ---- 2 k-steps of 32 ----
      #pragma unroll
      for (int ks = 0; ks < 2; ++ks) {
        bf16x8 av[4], bv[4];
        #pragma unroll
        for (int i = 0; i < 4; ++i) {
          int r = waveM * 64 + i * 16 + lm;
          int slot = (ks * 4 + quad) ^ (r & 7);
          av[i] = *(const bf16x8*)&As[(r << 6) + (slot << 3)];
        }
        #pragma unroll
        for (int j = 0; j < 4; ++j) {
          int c = waveN * 64 + j * 16 + lm;
          int slot = (ks * 4 + quad) ^ (c & 7);
          bv[j] = *(const bf16x8*)&Bs[(c << 6) + (slot << 3)];
        }
        #pragma unroll
        for (int i = 0; i < 4; ++i)
          #pragma unroll
          for (int j = 0; j < 4; ++j)
            acc[i][j] = __builtin_amdgcn_mfma_f32_16x16x32_bf16(av[i], bv[j], acc[i][j], 0, 0, 0);
      }
      __syncthreads();
    }
  }

  // ---- fused epilogue. C/D layout: col = lane&15, row = quad*4 + reg ----
  #pragma unroll
  for (int j = 0; j < 4; ++j) {
    const int col = colBase + waveN * 64 + j * 16 + lm;
    const float bias = b0[col] + b1[col] + b2[col];
    #pragma unroll
    for (int i = 0; i < 4; ++i) {
      #pragma unroll
      for (int r = 0; r < 4; ++r) {
        const int row = rowBase + waveM * 64 + i * 16 + quad * 4 + r;
        const size_t idx = (size_t)row * 1024 + col;
        float v = acc[i][j][r] + bias;
        if constexpr (MODE == MODE_Z) {
          outb[idx] = f2bf(1.f / (1.f + __expf(-v)));
        } else if constexpr (MODE == MODE_R) {
          float rv = 1.f / (1.f + __expf(-v));
          outb[idx] = f2bf(rv * bf2f(hb[idx]));
        } else if constexpr (MODE == MODE_S) {
          float avv = fabsf(v);
          float e = __expf(-2.f * avv);
          float st = (1.f - e) / (1.f + e);      // |tanh|
          st = v < 0.f ? -st : st;
          float zv = bf2f(zb[idx]);
          float hv = bf2f(hb[idx]);
          float s = (1.f - zv) * hv + zv * st;
          outf[idx] = s;
          outb[idx] = f2bf(s);
        } else {  // MODE_T
          outf[idx] = v > 0.f ? v : 0.f;
        }
      }
    }
  }
}

extern "C" void kernel_launch(void* const* d_in, const int* in_sizes, int n_in,
                              void* d_out, int out_size, void* d_ws, size_t ws_size,
                              hipStream_t stream) {
  (void)in_sizes; (void)n_in; (void)out_size; (void)ws_size;
  const float* x  = (const float*)d_in[0];   // [16384,1024]
  const float* h  = (const float*)d_in[1];   // [16384,1024]
  const float* a  = (const float*)d_in[2];   // [16384,2048]
  const float* W   = (const float*)d_in[3];  const float* bw  = (const float*)d_in[4];
  const float* Wz  = (const float*)d_in[5];  const float* bwz = (const float*)d_in[6];
  const float* Wr  = (const float*)d_in[7];  const float* bwr = (const float*)d_in[8];
  const float* U   = (const float*)d_in[9];  const float* bu  = (const float*)d_in[10];
  const float* Uz  = (const float*)d_in[11]; const float* buz = (const float*)d_in[12];
  const float* Ur  = (const float*)d_in[13]; const float* bur = (const float*)d_in[14];
  const float* C   = (const float*)d_in[15]; const float* bc  = (const float*)d_in[16];
  const float* Cz  = (const float*)d_in[17]; const float* bcz = (const float*)d_in[18];
  const float* Cr  = (const float*)d_in[19]; const float* bcr = (const float*)d_in[20];
  const float* Uo  = (const float*)d_in[21]; const float* buo = (const float*)d_in[22];
  const float* Vo  = (const float*)d_in[23]; const float* bvo = (const float*)d_in[24];
  const float* Co  = (const float*)d_in[25]; const float* bco = (const float*)d_in[26];

  const size_t M1 = 1024u * 1024u;           // 1M elements
  unsigned short* wsb = (unsigned short*)d_ws;
  // ws: 12 transposed bf16 weights (32 MB) + x_bf (32 MB) = 64 MB used.
  unsigned short* WzT = wsb + 0 * M1;
  unsigned short* UzT = wsb + 1 * M1;
  unsigned short* WrT = wsb + 2 * M1;
  unsigned short* UrT = wsb + 3 * M1;
  unsigned short* WT  = wsb + 4 * M1;
  unsigned short* UT  = wsb + 5 * M1;
  unsigned short* VoT = wsb + 6 * M1;
  unsigned short* UoT = wsb + 7 * M1;
  unsigned short* CzT = wsb + 8 * M1;        // 2M each from here
  unsigned short* CrT = wsb + 10 * M1;
  unsigned short* CT  = wsb + 12 * M1;
  unsigned short* CoT = wsb + 14 * M1;
  unsigned short* x_bf = wsb + 16 * M1;      // 16M elems

  // Scratch carved out of dead buffers (cross-launch ordering, see header):
  unsigned short* h_bf = (unsigned short*)((float*)d_out + 16 * M1); // d_out t-region
  unsigned short* a_bf = (unsigned short*)d_in[0];                   // x f32 dead after cvt_xh
  unsigned short* rh   = (unsigned short*)d_in[1];                   // h f32 dead after cvt_xh
  unsigned short* z_bf = (unsigned short*)d_in[1] + 16 * M1;
  unsigned short* s_bf = (unsigned short*)d_in[2];                   // a f32 dead after cvt_a

  float* s_out = (float*)d_out;
  float* t_out = (float*)d_out + 16 * M1;

  // 1) convert x,h (must precede a_bf overwriting x's buffer)
  cvt_xh<<<16384, 256, 0, stream>>>(x, h, x_bf, h_bf);
  // 2) convert a into x's (now dead) buffer
  cvt_a<<<16384, 256, 0, stream>>>(a, a_bf);
  // 3) all 12 weight transposes in one launch
  TArgs ta;
  const float* wsrc[12] = {Wz, Uz, Wr, Ur, W, U, Vo, Uo, Cz, Cr, C, Co};
  unsigned short* wdst[12] = {WzT, UzT, WrT, UrT, WT, UT, VoT, UoT, CzT, CrT, CT, CoT};
  for (int i = 0; i < 12; ++i) { ta.src[i] = wsrc[i]; ta.dst[i] = wdst[i]; }
  transpose_all<<<16384, dim3(32, 8), 0, stream>>>(ta);

  dim3 g(1024), b(256);
  gemm_fused<MODE_R><<<g, b, 0, stream>>>(x_bf, h_bf, a_bf, WrT, UrT, CrT,
                                          bwr, bur, bcr, h_bf, nullptr, nullptr, rh);
  gemm_fused<MODE_Z><<<g, b, 0, stream>>>(x_bf, h_bf, a_bf, WzT, UzT, CzT,
                                          bwz, buz, bcz, nullptr, nullptr, nullptr, z_bf);
  gemm_fused<MODE_S><<<g, b, 0, stream>>>(x_bf, rh, a_bf, WT, UT, CT,
                                          bw, bu, bc, h_bf, z_bf, s_out, s_bf);
  gemm_fused<MODE_T><<<g, b, 0, stream>>>(x_bf, s_bf, a_bf, VoT, UoT, CoT,
                                          bvo, buo, bco, nullptr, nullptr, t_out, nullptr);
}